// Round 2
// 147.689 us; speedup vs baseline: 1.0017x; 1.0017x over previous
//
#include <hip/hip_runtime.h>
#include <hip/hip_bf16.h>

// Causal SDPA, B=2 H=16 S=2048 D=64, fp32 in/out, bf16 MFMA compute.
// R6: R5 structure (32x32x16 swapped-QK^T, in-register softmax, 4 waves x
// 32 q-rows, double-buffered LDS, 1 barrier/tile) with the PV A-fragment
// half-exchange done via __shfl_xor(32)+select instead of
// v_permlane32_swap_b32 (whose half-swap direction is ambiguous and was the
// prime suspect in R5's absmax 4.36 failure). Row-sum moved BEFORE the
// exchange (sums each lane's own-row 32 values + cross-half shfl).

#define BHN 32
#define SEQ 2048
#define DIM 64
#define NW  4
#define LSTR 72  // LDS row stride (bf16): 144 B

typedef __attribute__((ext_vector_type(8)))  short    short8;
typedef __attribute__((ext_vector_type(4)))  short    short4v;
typedef __attribute__((ext_vector_type(4)))  float    float4v;
typedef __attribute__((ext_vector_type(16))) float    f32x16;
typedef __attribute__((ext_vector_type(4)))  unsigned uint4v;

__device__ __forceinline__ short f2b(float x) {
  __hip_bfloat16 h = __float2bfloat16(x);
  return __builtin_bit_cast(short, h);
}

// ---- pre-pass: K fp32->bf16 (same layout) + V fp32->bf16 transposed ------
__global__ __launch_bounds__(256) void prep_kernel(
    const float* __restrict__ K, const float* __restrict__ V,
    __hip_bfloat16* __restrict__ Kb, __hip_bfloat16* __restrict__ Vt) {
  __shared__ float t[64][65];
  const int bh = blockIdx.x, j = blockIdx.y, tid = threadIdx.x;
  const int r = tid >> 2, seg = (tid & 3) * 16;
  const size_t base = (size_t)bh * SEQ * DIM;
  {
    const float* ks = K + base + (size_t)(j * 64 + r) * DIM + seg;
    float4v k0 = *(const float4v*)(ks + 0);
    float4v k1 = *(const float4v*)(ks + 4);
    float4v k2 = *(const float4v*)(ks + 8);
    float4v k3 = *(const float4v*)(ks + 12);
    short8 a, b;
    a[0]=f2b(k0[0]); a[1]=f2b(k0[1]); a[2]=f2b(k0[2]); a[3]=f2b(k0[3]);
    a[4]=f2b(k1[0]); a[5]=f2b(k1[1]); a[6]=f2b(k1[2]); a[7]=f2b(k1[3]);
    b[0]=f2b(k2[0]); b[1]=f2b(k2[1]); b[2]=f2b(k2[2]); b[3]=f2b(k2[3]);
    b[4]=f2b(k3[0]); b[5]=f2b(k3[1]); b[6]=f2b(k3[2]); b[7]=f2b(k3[3]);
    __hip_bfloat16* kd = Kb + base + (size_t)(j * 64 + r) * DIM + seg;
    *(short8*)kd = a;
    *(short8*)(kd + 8) = b;
  }
  {
    const float* src = V + base + (size_t)(j * 64 + r) * DIM + seg;
    float4v f0 = *(const float4v*)(src + 0);
    float4v f1 = *(const float4v*)(src + 4);
    float4v f2 = *(const float4v*)(src + 8);
    float4v f3 = *(const float4v*)(src + 12);
    *(float4v*)&t[r][seg + 0]  = f0;
    *(float4v*)&t[r][seg + 4]  = f1;
    *(float4v*)&t[r][seg + 8]  = f2;
    *(float4v*)&t[r][seg + 12] = f3;
    __syncthreads();
    short8 o0, o1;
    #pragma unroll
    for (int i = 0; i < 8; ++i) o0[i] = f2b(t[seg + i][r]);
    #pragma unroll
    for (int i = 0; i < 8; ++i) o1[i] = f2b(t[seg + 8 + i][r]);
    __hip_bfloat16* dst = Vt + (size_t)bh * DIM * SEQ + (size_t)r * SEQ + j * 64 + seg;
    *(short8*)dst = o0;
    *(short8*)(dst + 8) = o1;
  }
}

// ---------------------------- main flash kernel ---------------------------
// 4 waves x 32 q-rows, 32x32x16 MFMA, swapped QK^T, in-register softmax.
__global__ __launch_bounds__(256, 2) void fattn6(
    const float* __restrict__ Qg, const __hip_bfloat16* __restrict__ Kb,
    const __hip_bfloat16* __restrict__ Vt, float* __restrict__ Og) {
  __shared__ alignas(16) __hip_bfloat16 kt[2][64][LSTR];
  __shared__ alignas(16) __hip_bfloat16 vt[2][64][LSTR];
  __shared__ float lbuf[NW][32];

  const int bh   = blockIdx.x;
  const int qt   = gridDim.y - 1 - blockIdx.y;  // longest blocks first
  const int tid  = threadIdx.x;
  const int w    = tid >> 6;
  const int lane = tid & 63;
  const int l31  = lane & 31;
  const int hi   = lane >> 5;
  const size_t base  = (size_t)bh * SEQ * DIM;
  const size_t baseV = (size_t)bh * DIM * SEQ;
  const int q0   = qt * 128;
  const int jmax = 2 * qt + 1;

  const float QSCALE = 0.125f * 1.44269504088896340736f;  // scale * log2(e)

  // Q fragments (B-operand of swapped QK^T): qf[s][i] = Q[q0+32w+l31][16s+8hi+i]
  short8 qf[4];
  {
    const float* qp = Qg + base + (size_t)(q0 + 32 * w + l31) * DIM + 8 * hi;
    #pragma unroll
    for (int s = 0; s < 4; ++s) {
      float4v f0 = *(const float4v*)(qp + 16 * s);
      float4v f1 = *(const float4v*)(qp + 16 * s + 4);
      short8 qv;
      qv[0] = f2b(f0[0] * QSCALE); qv[1] = f2b(f0[1] * QSCALE);
      qv[2] = f2b(f0[2] * QSCALE); qv[3] = f2b(f0[3] * QSCALE);
      qv[4] = f2b(f1[0] * QSCALE); qv[5] = f2b(f1[1] * QSCALE);
      qv[6] = f2b(f1[2] * QSCALE); qv[7] = f2b(f1[3] * QSCALE);
      qf[s] = qv;
    }
  }

  f32x16 o0, o1;
  #pragma unroll
  for (int i = 0; i < 16; ++i) { o0[i] = 0.f; o1[i] = 0.f; }
  float acc_l = 0.f;

  const int srow = tid >> 2;          // 0..63
  const int scol = (tid & 3) * 16;    // 0,16,32,48

  // prologue: tile 0 global -> regs -> LDS buf 0
  short8 ka0, ka1, va0, va1;
  {
    const __hip_bfloat16* kp = Kb + base + (size_t)srow * DIM + scol;
    ka0 = *(const short8*)kp; ka1 = *(const short8*)(kp + 8);
    const __hip_bfloat16* vp = Vt + baseV + (size_t)srow * SEQ + scol;
    va0 = *(const short8*)vp; va1 = *(const short8*)(vp + 8);
  }
  *(short8*)&kt[0][srow][scol]     = ka0;
  *(short8*)&kt[0][srow][scol + 8] = ka1;
  *(short8*)&vt[0][srow][scol]     = va0;
  *(short8*)&vt[0][srow][scol + 8] = va1;
  __syncthreads();

  for (int j = 0; j <= jmax; ++j) {
    const int cur = j & 1;

    // issue global loads for tile j+1 early (latency hidden by QK^T/softmax)
    if (j < jmax) {
      const int kb = (j + 1) * 64;
      const __hip_bfloat16* kp = Kb + base + (size_t)(kb + srow) * DIM + scol;
      ka0 = *(const short8*)kp; ka1 = *(const short8*)(kp + 8);
      const __hip_bfloat16* vp = Vt + baseV + (size_t)srow * SEQ + kb + scol;
      va0 = *(const short8*)vp; va1 = *(const short8*)(vp + 8);
    }

    const bool act = (64 * j <= q0 + 32 * w + 31);  // wave-uniform
    unsigned pw[16];

    if (act) {
      // ---- S^T = K · Q^T  (C: col=lane&31=q, rows over regs = k_rel)
      f32x16 p0, p1;
      #pragma unroll
      for (int i = 0; i < 16; ++i) { p0[i] = 0.f; p1[i] = 0.f; }
      __builtin_amdgcn_s_setprio(1);
      #pragma unroll
      for (int s = 0; s < 4; ++s) {
        short8 a0 = *(const short8*)&kt[cur][l31][16 * s + 8 * hi];
        short8 a1 = *(const short8*)&kt[cur][32 + l31][16 * s + 8 * hi];
        p0 = __builtin_amdgcn_mfma_f32_32x32x16_bf16(a0, qf[s], p0, 0, 0, 0);
        p1 = __builtin_amdgcn_mfma_f32_32x32x16_bf16(a1, qf[s], p1, 0, 0, 0);
      }
      __builtin_amdgcn_s_setprio(0);

      // ---- causal mask (diagonal tiles only)
      if (64 * j + 63 > q0 + 32 * w) {
        const int qg  = q0 + 32 * w + l31;
        const int kb0 = 64 * j + 4 * hi;
        #pragma unroll
        for (int r = 0; r < 16; ++r) {
          const int kr = kb0 + (r & 3) + 8 * (r >> 2);
          if (kr > qg)      p0[r] = -1e30f;
          if (kr + 32 > qg) p1[r] = -1e30f;
        }
      }

      // ---- P = exp2(S), pack to bf16 in-register
      #pragma unroll
      for (int i = 0; i < 16; ++i) {
        p0[i] = __builtin_amdgcn_exp2f(p0[i]);
        p1[i] = __builtin_amdgcn_exp2f(p1[i]);
      }
      #pragma unroll
      for (int i = 0; i < 8; ++i)
        asm("v_cvt_pk_bf16_f32 %0, %1, %2"
            : "=v"(pw[i]) : "v"(p0[2 * i]), "v"(p0[2 * i + 1]));
      #pragma unroll
      for (int i = 0; i < 8; ++i)
        asm("v_cvt_pk_bf16_f32 %0, %1, %2"
            : "=v"(pw[8 + i]) : "v"(p1[2 * i]), "v"(p1[2 * i + 1]));

      // ---- row sum from the SAME bf16-rounded values (before exchange;
      //      each lane holds 32 values of its own q-row; partner half via shfl)
      float rs = 0.f;
      #pragma unroll
      for (int i = 0; i < 16; ++i) {
        rs += __builtin_bit_cast(float, pw[i] << 16);
        rs += __builtin_bit_cast(float, pw[i] & 0xffff0000u);
      }
      rs += __shfl_xor(rs, 32, 64);
      acc_l += rs;
    }

    // commit tile j+1 to the other LDS buffer (vmcnt wait lands here;
    // PV below overlaps the ds_write latency)
    if (j < jmax) {
      const int nb = cur ^ 1;
      *(short8*)&kt[nb][srow][scol]     = ka0;
      *(short8*)&kt[nb][srow][scol + 8] = ka1;
      *(short8*)&vt[nb][srow][scol]     = va0;
      *(short8*)&vt[nb][srow][scol + 8] = va1;
    }

    if (act) {
      // ---- O += P V   (A = P frag built via semantics-safe half-exchange,
      //      B = V from LDS). Lane (hi,l31) needs P[q=l31][16t+8hi+{0..7}].
      #pragma unroll
      for (int t = 0; t < 4; ++t) {
        const unsigned x0 = __shfl_xor(pw[4 * t + 0], 32, 64);
        const unsigned x1 = __shfl_xor(pw[4 * t + 1], 32, 64);
        const unsigned x2 = __shfl_xor(pw[4 * t + 2], 32, 64);
        const unsigned x3 = __shfl_xor(pw[4 * t + 3], 32, 64);
        const unsigned f0 = hi ? x2 : pw[4 * t + 0];
        const unsigned f1 = hi ? x3 : pw[4 * t + 1];
        const unsigned f2 = hi ? pw[4 * t + 2] : x0;
        const unsigned f3 = hi ? pw[4 * t + 3] : x1;
        uint4v u = {f0, f1, f2, f3};
        short8 pa = __builtin_bit_cast(short8, u);
        short8 b0 = *(const short8*)&vt[cur][l31][16 * t + 8 * hi];
        short8 b1 = *(const short8*)&vt[cur][32 + l31][16 * t + 8 * hi];
        __builtin_amdgcn_s_setprio(1);
        o0 = __builtin_amdgcn_mfma_f32_32x32x16_bf16(pa, b0, o0, 0, 0, 0);
        o1 = __builtin_amdgcn_mfma_f32_32x32x16_bf16(pa, b1, o1, 0, 0, 0);
        __builtin_amdgcn_s_setprio(0);
      }
    }
    __syncthreads();
  }

  // ---- epilogue: redistribute l (lane&31-indexed) to reg-row-indexed O
  if (lane < 32) lbuf[w][l31] = acc_l;
  __syncthreads();
  const float* lb = lbuf[w];
  float* op = Og + base + (size_t)(q0 + 32 * w) * DIM + l31;
  #pragma unroll
  for (int r = 0; r < 16; ++r) {
    const int row = (r & 3) + 8 * (r >> 2) + 4 * hi;
    const float iv = 1.0f / lb[row];
    op[(size_t)row * DIM]      = o0[r] * iv;
    op[(size_t)row * DIM + 32] = o1[r] * iv;
  }
}

// --------------- fallback if ws too small: in-kernel cast -----------------
__global__ __launch_bounds__(256) void fattn_ref(
    const float* __restrict__ Qg, const float* __restrict__ Kg,
    const float* __restrict__ Vg, float* __restrict__ Og) {
  __shared__ alignas(16) __hip_bfloat16 kt[64][LSTR];
  __shared__ alignas(16) __hip_bfloat16 vt[64][LSTR];
  __shared__ alignas(16) __hip_bfloat16 pt[NW][16][LSTR];

  const int bh   = blockIdx.x;
  const int qt   = gridDim.y - 1 - blockIdx.y;
  const int tid  = threadIdx.x;
  const int wave = tid >> 6;
  const int lane = tid & 63;
  const int ln   = lane & 15;
  const int quad = lane >> 4;
  const size_t base = (size_t)bh * SEQ * DIM;
  const int q0 = qt * 64;

  const float QSCALE = 0.125f * 1.44269504088896340736f;
  short8 qf[2];
  {
    const int qrow = q0 + wave * 16 + ln;
    const float* qp = Qg + base + (size_t)qrow * DIM + quad * 8;
    #pragma unroll
    for (int kk = 0; kk < 2; ++kk) {
      float4v f0 = *(const float4v*)(qp + kk * 32);
      float4v f1 = *(const float4v*)(qp + kk * 32 + 4);
      short8 qv;
      qv[0] = f2b(f0[0] * QSCALE); qv[1] = f2b(f0[1] * QSCALE);
      qv[2] = f2b(f0[2] * QSCALE); qv[3] = f2b(f0[3] * QSCALE);
      qv[4] = f2b(f1[0] * QSCALE); qv[5] = f2b(f1[1] * QSCALE);
      qv[6] = f2b(f1[2] * QSCALE); qv[7] = f2b(f1[3] * QSCALE);
      qf[kk] = qv;
    }
  }
  float4v o[4];
  #pragma unroll
  for (int dt = 0; dt < 4; ++dt) { float4v z = {0.f,0.f,0.f,0.f}; o[dt] = z; }
  float l_i[4] = {0.f, 0.f, 0.f, 0.f};

  for (int j = 0; j <= qt; ++j) {
    const int kbase = j * 64;
    __syncthreads();
    {
      const int r = tid >> 4, c = (tid & 15) * 4;
      #pragma unroll
      for (int it = 0; it < 4; ++it) {
        const int row = it * 16 + r;
        float4v f = *(const float4v*)(Kg + base + (size_t)(kbase + row) * DIM + c);
        short4v sv; sv[0]=f2b(f[0]); sv[1]=f2b(f[1]); sv[2]=f2b(f[2]); sv[3]=f2b(f[3]);
        *(short4v*)&kt[row][c] = sv;
      }
      const int d = tid & 63, s0 = (tid >> 6) * 4;
      #pragma unroll
      for (int it = 0; it < 4; ++it) {
        const int sk = it * 16 + s0;
        short4v sv;
        sv[0] = f2b(Vg[base + (size_t)(kbase + sk + 0) * DIM + d]);
        sv[1] = f2b(Vg[base + (size_t)(kbase + sk + 1) * DIM + d]);
        sv[2] = f2b(Vg[base + (size_t)(kbase + sk + 2) * DIM + d]);
        sv[3] = f2b(Vg[base + (size_t)(kbase + sk + 3) * DIM + d]);
        *(short4v*)&vt[d][sk] = sv;
      }
    }
    __syncthreads();

    float4v s[4];
    #pragma unroll
    for (int nt = 0; nt < 4; ++nt) {
      short8 b0 = *(const short8*)&kt[nt * 16 + ln][quad * 8];
      short8 b1 = *(const short8*)&kt[nt * 16 + ln][32 + quad * 8];
      float4v acc = {0.f,0.f,0.f,0.f};
      acc = __builtin_amdgcn_mfma_f32_16x16x32_bf16(qf[0], b0, acc, 0, 0, 0);
      acc = __builtin_amdgcn_mfma_f32_16x16x32_bf16(qf[1], b1, acc, 0, 0, 0);
      s[nt] = acc;
    }
    if (j == qt) {
      #pragma unroll
      for (int nt = 0; nt < 4; ++nt) {
        const int col = nt * 16 + ln;
        #pragma unroll
        for (int rg = 0; rg < 4; ++rg)
          if (col > wave * 16 + quad * 4 + rg) s[nt][rg] = -1e30f;
      }
    }
    #pragma unroll
    for (int rg = 0; rg < 4; ++rg) {
      float p0 = __builtin_amdgcn_exp2f(s[0][rg]);
      float p1 = __builtin_amdgcn_exp2f(s[1][rg]);
      float p2 = __builtin_amdgcn_exp2f(s[2][rg]);
      float p3 = __builtin_amdgcn_exp2f(s[3][rg]);
      s[0][rg]=p0; s[1][rg]=p1; s[2][rg]=p2; s[3][rg]=p3;
      float rs = (p0 + p1) + (p2 + p3);
      rs += __shfl_xor(rs, 1, 64); rs += __shfl_xor(rs, 2, 64);
      rs += __shfl_xor(rs, 4, 64); rs += __shfl_xor(rs, 8, 64);
      l_i[rg] += rs;
    }
    #pragma unroll
    for (int nt = 0; nt < 4; ++nt)
      #pragma unroll
      for (int rg = 0; rg < 4; ++rg)
        pt[wave][quad * 4 + rg][nt * 16 + ln] = __float2bfloat16(s[nt][rg]);
    short8 pa0 = *(const short8*)&pt[wave][ln][quad * 8];
    short8 pa1 = *(const short8*)&pt[wave][ln][32 + quad * 8];
    #pragma unroll
    for (int dt = 0; dt < 4; ++dt) {
      short8 vb0 = *(const short8*)&vt[dt * 16 + ln][quad * 8];
      short8 vb1 = *(const short8*)&vt[dt * 16 + ln][32 + quad * 8];
      o[dt] = __builtin_amdgcn_mfma_f32_16x16x32_bf16(pa0, vb0, o[dt], 0, 0, 0);
      o[dt] = __builtin_amdgcn_mfma_f32_16x16x32_bf16(pa1, vb1, o[dt], 0, 0, 0);
    }
  }
  #pragma unroll
  for (int rg = 0; rg < 4; ++rg) {
    const float inv = 1.0f / l_i[rg];
    const int row = q0 + wave * 16 + quad * 4 + rg;
    float* op = Og + base + (size_t)row * DIM + ln;
    #pragma unroll
    for (int dt = 0; dt < 4; ++dt) op[dt * 16] = o[dt][rg] * inv;
  }
}

extern "C" void kernel_launch(void* const* d_in, const int* in_sizes, int n_in,
                              void* d_out, int out_size, void* d_ws, size_t ws_size,
                              hipStream_t stream) {
  (void)in_sizes; (void)n_in; (void)out_size;
  const float* Q = (const float*)d_in[0];
  const float* K = (const float*)d_in[1];
  const float* V = (const float*)d_in[2];
  float* O = (float*)d_out;
  const size_t need = (size_t)2 * BHN * SEQ * DIM * sizeof(__hip_bfloat16); // 16 MB
  if (ws_size >= need) {
    __hip_bfloat16* Kb = (__hip_bfloat16*)d_ws;
    __hip_bfloat16* Vt = Kb + (size_t)BHN * SEQ * DIM;
    prep_kernel<<<dim3(BHN, SEQ / 64), 256, 0, stream>>>(K, V, Kb, Vt);
    fattn6<<<dim3(BHN, SEQ / 128), 256, 0, stream>>>(Q, Kb, Vt, O);
  } else {
    fattn_ref<<<dim3(BHN, SEQ / 64), 256, 0, stream>>>(Q, K, V, O);
  }
}

// Round 3
// 140.122 us; speedup vs baseline: 1.0558x; 1.0540x over previous
//
#include <hip/hip_runtime.h>
#include <hip/hip_bf16.h>

// Causal SDPA, B=2 H=16 S=2048 D=64, fp32 in/out, bf16 MFMA compute.
// R7: fix R6's occupancy collapse (12.9%) + critical-path latency.
//  - 2-wave blocks, 64 q-rows -> grid 32x32 = 1024 blocks = 4 blocks/CU
//    (4 independent barrier domains/CU, no act-divergence: both waves
//    active on every k-tile).
//  - NO half-exchange at all: prep_kernel stores V^T with k-columns
//    permuted per 16-group ([0..3,8..11,4..7,12..15]) so {pw[4t..4t+3]}
//    is directly the PV A-fragment (A/B share the same per-group k
//    bijection -> contraction invariant). Removes 16 ds_bpermute/tile.
//  - Row-sum via ones-MFMA on the PV A-fragments (4 MFMA/tile on the
//    idle MFMA pipe) -> l reg-indexed like o0; no VALU rowsum, no lbuf.

#define BHN 32
#define SEQ 2048
#define DIM 64
#define LSTR 72  // LDS row stride (bf16): 144 B, conflict-free (measured 0)

typedef __attribute__((ext_vector_type(8)))  short    short8;
typedef __attribute__((ext_vector_type(4)))  short    short4v;
typedef __attribute__((ext_vector_type(4)))  float    float4v;
typedef __attribute__((ext_vector_type(16))) float    f32x16;
typedef __attribute__((ext_vector_type(4)))  unsigned uint4v;

__device__ __forceinline__ short f2b(float x) {
  __hip_bfloat16 h = __float2bfloat16(x);
  return __builtin_bit_cast(short, h);
}

// ---- pre-pass: K fp32->bf16 (same layout) + V fp32->bf16 transposed,
//      with per-16-k-group column permutation [0..3, 8..11, 4..7, 12..15].
__global__ __launch_bounds__(256) void prep_kernel(
    const float* __restrict__ K, const float* __restrict__ V,
    __hip_bfloat16* __restrict__ Kb, __hip_bfloat16* __restrict__ Vt) {
  __shared__ float t[64][65];
  const int bh = blockIdx.x, j = blockIdx.y, tid = threadIdx.x;
  const int r = tid >> 2, seg = (tid & 3) * 16;
  const size_t base = (size_t)bh * SEQ * DIM;
  {
    const float* ks = K + base + (size_t)(j * 64 + r) * DIM + seg;
    float4v k0 = *(const float4v*)(ks + 0);
    float4v k1 = *(const float4v*)(ks + 4);
    float4v k2 = *(const float4v*)(ks + 8);
    float4v k3 = *(const float4v*)(ks + 12);
    short8 a, b;
    a[0]=f2b(k0[0]); a[1]=f2b(k0[1]); a[2]=f2b(k0[2]); a[3]=f2b(k0[3]);
    a[4]=f2b(k1[0]); a[5]=f2b(k1[1]); a[6]=f2b(k1[2]); a[7]=f2b(k1[3]);
    b[0]=f2b(k2[0]); b[1]=f2b(k2[1]); b[2]=f2b(k2[2]); b[3]=f2b(k2[3]);
    b[4]=f2b(k3[0]); b[5]=f2b(k3[1]); b[6]=f2b(k3[2]); b[7]=f2b(k3[3]);
    __hip_bfloat16* kd = Kb + base + (size_t)(j * 64 + r) * DIM + seg;
    *(short8*)kd = a;
    *(short8*)(kd + 8) = b;
  }
  {
    const float* src = V + base + (size_t)(j * 64 + r) * DIM + seg;
    float4v f0 = *(const float4v*)(src + 0);
    float4v f1 = *(const float4v*)(src + 4);
    float4v f2 = *(const float4v*)(src + 8);
    float4v f3 = *(const float4v*)(src + 12);
    *(float4v*)&t[r][seg + 0]  = f0;
    *(float4v*)&t[r][seg + 4]  = f1;
    *(float4v*)&t[r][seg + 8]  = f2;
    *(float4v*)&t[r][seg + 12] = f3;
    __syncthreads();
    // stored order within this 16-k group: [0,1,2,3, 8,9,10,11, 4,5,6,7, 12,13,14,15]
    short8 n0, n1;
    #pragma unroll
    for (int i = 0; i < 4; ++i) {
      n0[i]     = f2b(t[seg + i][r]);        // k = 0..3
      n0[4 + i] = f2b(t[seg + 8 + i][r]);    // k = 8..11
      n1[i]     = f2b(t[seg + 4 + i][r]);    // k = 4..7
      n1[4 + i] = f2b(t[seg + 12 + i][r]);   // k = 12..15
    }
    __hip_bfloat16* dst = Vt + (size_t)bh * DIM * SEQ + (size_t)r * SEQ + j * 64 + seg;
    *(short8*)dst = n0;
    *(short8*)(dst + 8) = n1;
  }
}

// ---------------------------- main flash kernel ---------------------------
// 2 waves x 32 q-rows (64 rows/block), 32x32x16 MFMA, swapped QK^T,
// in-register softmax, ones-MFMA rowsum, pre-permuted V (no lane exchange).
__global__ __launch_bounds__(128, 2) void fattn7(
    const float* __restrict__ Qg, const __hip_bfloat16* __restrict__ Kb,
    const __hip_bfloat16* __restrict__ Vt, float* __restrict__ Og) {
  __shared__ alignas(16) __hip_bfloat16 kt[2][64][LSTR];
  __shared__ alignas(16) __hip_bfloat16 vt[2][64][LSTR];

  const int bh   = blockIdx.x;
  const int qt   = gridDim.y - 1 - blockIdx.y;  // longest blocks first
  const int tid  = threadIdx.x;
  const int w    = tid >> 6;
  const int lane = tid & 63;
  const int l31  = lane & 31;
  const int hi   = lane >> 5;
  const size_t base  = (size_t)bh * SEQ * DIM;
  const size_t baseV = (size_t)bh * DIM * SEQ;
  const int q0   = qt * 64;

  const float QSCALE = 0.125f * 1.44269504088896340736f;  // scale * log2(e)

  // Q fragments (B-operand of swapped QK^T): qf[s][i] = Q[q0+32w+l31][16s+8hi+i]
  short8 qf[4];
  {
    const float* qp = Qg + base + (size_t)(q0 + 32 * w + l31) * DIM + 8 * hi;
    #pragma unroll
    for (int s = 0; s < 4; ++s) {
      float4v f0 = *(const float4v*)(qp + 16 * s);
      float4v f1 = *(const float4v*)(qp + 16 * s + 4);
      short8 qv;
      qv[0] = f2b(f0[0] * QSCALE); qv[1] = f2b(f0[1] * QSCALE);
      qv[2] = f2b(f0[2] * QSCALE); qv[3] = f2b(f0[3] * QSCALE);
      qv[4] = f2b(f1[0] * QSCALE); qv[5] = f2b(f1[1] * QSCALE);
      qv[6] = f2b(f1[2] * QSCALE); qv[7] = f2b(f1[3] * QSCALE);
      qf[s] = qv;
    }
  }

  short8 ones;
  #pragma unroll
  for (int x = 0; x < 8; ++x) ones[x] = (short)0x3F80;  // bf16 1.0

  f32x16 o0, o1, l16;
  #pragma unroll
  for (int i = 0; i < 16; ++i) { o0[i] = 0.f; o1[i] = 0.f; l16[i] = 0.f; }

  // staging: 128 threads cover 64 rows x 64 cols (32 cols/thread)
  const int srow = tid >> 1;          // 0..63
  const int scol = (tid & 1) * 32;    // 0 or 32

  short8 sk[4], sv[4];
  {
    const __hip_bfloat16* kp = Kb + base + (size_t)srow * DIM + scol;
    const __hip_bfloat16* vp = Vt + baseV + (size_t)srow * SEQ + scol;
    #pragma unroll
    for (int i = 0; i < 4; ++i) { sk[i] = *(const short8*)(kp + 8 * i); }
    #pragma unroll
    for (int i = 0; i < 4; ++i) { sv[i] = *(const short8*)(vp + 8 * i); }
  }
  #pragma unroll
  for (int i = 0; i < 4; ++i) {
    *(short8*)&kt[0][srow][scol + 8 * i] = sk[i];
    *(short8*)&vt[0][srow][scol + 8 * i] = sv[i];
  }
  __syncthreads();

  for (int j = 0; j <= qt; ++j) {
    const int cur = j & 1;

    // issue global loads for tile j+1 early (hidden under QK^T + softmax)
    if (j < qt) {
      const int kb = (j + 1) * 64;
      const __hip_bfloat16* kp = Kb + base + (size_t)(kb + srow) * DIM + scol;
      const __hip_bfloat16* vp = Vt + baseV + (size_t)srow * SEQ + kb + scol;
      #pragma unroll
      for (int i = 0; i < 4; ++i) { sk[i] = *(const short8*)(kp + 8 * i); }
      #pragma unroll
      for (int i = 0; i < 4; ++i) { sv[i] = *(const short8*)(vp + 8 * i); }
    }

    // ---- S^T = K · Q^T  (D: col=lane&31=q, rows over regs = k_rel)
    f32x16 p0, p1;
    #pragma unroll
    for (int i = 0; i < 16; ++i) { p0[i] = 0.f; p1[i] = 0.f; }
    __builtin_amdgcn_s_setprio(1);
    #pragma unroll
    for (int s = 0; s < 4; ++s) {
      short8 a0 = *(const short8*)&kt[cur][l31][16 * s + 8 * hi];
      short8 a1 = *(const short8*)&kt[cur][32 + l31][16 * s + 8 * hi];
      p0 = __builtin_amdgcn_mfma_f32_32x32x16_bf16(a0, qf[s], p0, 0, 0, 0);
      p1 = __builtin_amdgcn_mfma_f32_32x32x16_bf16(a1, qf[s], p1, 0, 0, 0);
    }
    __builtin_amdgcn_s_setprio(0);

    // ---- causal mask (diagonal tile only)
    if (j == qt) {
      const int qg  = q0 + 32 * w + l31;
      const int kb0 = 64 * j + 4 * hi;
      #pragma unroll
      for (int r = 0; r < 16; ++r) {
        const int kr = kb0 + (r & 3) + 8 * (r >> 2);
        if (kr > qg)      p0[r] = -1e30f;
        if (kr + 32 > qg) p1[r] = -1e30f;
      }
    }

    // ---- P = exp2(S), pack to bf16 in-register (natural order; V was
    //      pre-permuted to match, so pw IS the PV A-fragment)
    #pragma unroll
    for (int i = 0; i < 16; ++i) {
      p0[i] = __builtin_amdgcn_exp2f(p0[i]);
      p1[i] = __builtin_amdgcn_exp2f(p1[i]);
    }
    unsigned pw[16];
    #pragma unroll
    for (int i = 0; i < 8; ++i)
      asm("v_cvt_pk_bf16_f32 %0, %1, %2"
          : "=v"(pw[i]) : "v"(p0[2 * i]), "v"(p0[2 * i + 1]));
    #pragma unroll
    for (int i = 0; i < 8; ++i)
      asm("v_cvt_pk_bf16_f32 %0, %1, %2"
          : "=v"(pw[8 + i]) : "v"(p1[2 * i]), "v"(p1[2 * i + 1]));

    // commit tile j+1 to the other LDS buffer (vmcnt wait lands here;
    // PV below overlaps the ds_write latency)
    if (j < qt) {
      const int nb = cur ^ 1;
      #pragma unroll
      for (int i = 0; i < 4; ++i) {
        *(short8*)&kt[nb][srow][scol + 8 * i] = sk[i];
        *(short8*)&vt[nb][srow][scol + 8 * i] = sv[i];
      }
    }

    // ---- O += P V, l += P·1 (rowsum on MFMA pipe, reg-indexed like o)
    __builtin_amdgcn_s_setprio(1);
    #pragma unroll
    for (int t = 0; t < 4; ++t) {
      uint4v u = {pw[4 * t], pw[4 * t + 1], pw[4 * t + 2], pw[4 * t + 3]};
      short8 pa = __builtin_bit_cast(short8, u);
      short8 b0 = *(const short8*)&vt[cur][l31][16 * t + 8 * hi];
      short8 b1 = *(const short8*)&vt[cur][32 + l31][16 * t + 8 * hi];
      o0  = __builtin_amdgcn_mfma_f32_32x32x16_bf16(pa, b0, o0, 0, 0, 0);
      o1  = __builtin_amdgcn_mfma_f32_32x32x16_bf16(pa, b1, o1, 0, 0, 0);
      l16 = __builtin_amdgcn_mfma_f32_32x32x16_bf16(pa, ones, l16, 0, 0, 0);
    }
    __builtin_amdgcn_s_setprio(0);
    __syncthreads();
  }

  // ---- epilogue: O /= l   (l16[r] holds rowsum of the same q-row as o[r])
  float* op = Og + base + (size_t)(q0 + 32 * w) * DIM + l31;
  #pragma unroll
  for (int r = 0; r < 16; ++r) {
    const int row = (r & 3) + 8 * (r >> 2) + 4 * hi;
    const float iv = 1.0f / l16[r];
    op[(size_t)row * DIM]      = o0[r] * iv;
    op[(size_t)row * DIM + 32] = o1[r] * iv;
  }
}

// --------------- fallback if ws too small: in-kernel cast -----------------
__global__ __launch_bounds__(256) void fattn_ref(
    const float* __restrict__ Qg, const float* __restrict__ Kg,
    const float* __restrict__ Vg, float* __restrict__ Og) {
  __shared__ alignas(16) __hip_bfloat16 kt[64][LSTR];
  __shared__ alignas(16) __hip_bfloat16 vt[64][LSTR];
  __shared__ alignas(16) __hip_bfloat16 pt[4][16][LSTR];

  const int bh   = blockIdx.x;
  const int qt   = gridDim.y - 1 - blockIdx.y;
  const int tid  = threadIdx.x;
  const int wave = tid >> 6;
  const int lane = tid & 63;
  const int ln   = lane & 15;
  const int quad = lane >> 4;
  const size_t base = (size_t)bh * SEQ * DIM;
  const int q0 = qt * 64;

  const float QSCALE = 0.125f * 1.44269504088896340736f;
  short8 qf[2];
  {
    const int qrow = q0 + wave * 16 + ln;
    const float* qp = Qg + base + (size_t)qrow * DIM + quad * 8;
    #pragma unroll
    for (int kk = 0; kk < 2; ++kk) {
      float4v f0 = *(const float4v*)(qp + kk * 32);
      float4v f1 = *(const float4v*)(qp + kk * 32 + 4);
      short8 qv;
      qv[0] = f2b(f0[0] * QSCALE); qv[1] = f2b(f0[1] * QSCALE);
      qv[2] = f2b(f0[2] * QSCALE); qv[3] = f2b(f0[3] * QSCALE);
      qv[4] = f2b(f1[0] * QSCALE); qv[5] = f2b(f1[1] * QSCALE);
      qv[6] = f2b(f1[2] * QSCALE); qv[7] = f2b(f1[3] * QSCALE);
      qf[kk] = qv;
    }
  }
  float4v o[4];
  #pragma unroll
  for (int dt = 0; dt < 4; ++dt) { float4v z = {0.f,0.f,0.f,0.f}; o[dt] = z; }
  float l_i[4] = {0.f, 0.f, 0.f, 0.f};

  for (int j = 0; j <= qt; ++j) {
    const int kbase = j * 64;
    __syncthreads();
    {
      const int r = tid >> 4, c = (tid & 15) * 4;
      #pragma unroll
      for (int it = 0; it < 4; ++it) {
        const int row = it * 16 + r;
        float4v f = *(const float4v*)(Kg + base + (size_t)(kbase + row) * DIM + c);
        short4v sv; sv[0]=f2b(f[0]); sv[1]=f2b(f[1]); sv[2]=f2b(f[2]); sv[3]=f2b(f[3]);
        *(short4v*)&kt[row][c] = sv;
      }
      const int d = tid & 63, s0 = (tid >> 6) * 4;
      #pragma unroll
      for (int it = 0; it < 4; ++it) {
        const int sk = it * 16 + s0;
        short4v sv;
        sv[0] = f2b(Vg[base + (size_t)(kbase + sk + 0) * DIM + d]);
        sv[1] = f2b(Vg[base + (size_t)(kbase + sk + 1) * DIM + d]);
        sv[2] = f2b(Vg[base + (size_t)(kbase + sk + 2) * DIM + d]);
        sv[3] = f2b(Vg[base + (size_t)(kbase + sk + 3) * DIM + d]);
        *(short4v*)&vt[d][sk] = sv;
      }
    }
    __syncthreads();

    float4v s[4];
    #pragma unroll
    for (int nt = 0; nt < 4; ++nt) {
      short8 b0 = *(const short8*)&kt[nt * 16 + ln][quad * 8];
      short8 b1 = *(const short8*)&kt[nt * 16 + ln][32 + quad * 8];
      float4v acc = {0.f,0.f,0.f,0.f};
      acc = __builtin_amdgcn_mfma_f32_16x16x32_bf16(qf[0], b0, acc, 0, 0, 0);
      acc = __builtin_amdgcn_mfma_f32_16x16x32_bf16(qf[1], b1, acc, 0, 0, 0);
      s[nt] = acc;
    }
    if (j == qt) {
      #pragma unroll
      for (int nt = 0; nt < 4; ++nt) {
        const int col = nt * 16 + ln;
        #pragma unroll
        for (int rg = 0; rg < 4; ++rg)
          if (col > wave * 16 + quad * 4 + rg) s[nt][rg] = -1e30f;
      }
    }
    #pragma unroll
    for (int rg = 0; rg < 4; ++rg) {
      float p0 = __builtin_amdgcn_exp2f(s[0][rg]);
      float p1 = __builtin_amdgcn_exp2f(s[1][rg]);
      float p2 = __builtin_amdgcn_exp2f(s[2][rg]);
      float p3 = __builtin_amdgcn_exp2f(s[3][rg]);
      s[0][rg]=p0; s[1][rg]=p1; s[2][rg]=p2; s[3][rg]=p3;
      float rs = (p0 + p1) + (p2 + p3);
      rs += __shfl_xor(rs, 1, 64); rs += __shfl_xor(rs, 2, 64);
      rs += __shfl_xor(rs, 4, 64); rs += __shfl_xor(rs, 8, 64);
      l_i[rg] += rs;
    }
    #pragma unroll
    for (int nt = 0; nt < 4; ++nt)
      #pragma unroll
      for (int rg = 0; rg < 4; ++rg)
        pt[wave][quad * 4 + rg][nt * 16 + ln] = __float2bfloat16(s[nt][rg]);
    short8 pa0 = *(const short8*)&pt[wave][ln][quad * 8];
    short8 pa1 = *(const short8*)&pt[wave][ln][32 + quad * 8];
    #pragma unroll
    for (int dt = 0; dt < 4; ++dt) {
      short8 vb0 = *(const short8*)&vt[dt * 16 + ln][quad * 8];
      short8 vb1 = *(const short8*)&vt[dt * 16 + ln][32 + quad * 8];
      o[dt] = __builtin_amdgcn_mfma_f32_16x16x32_bf16(pa0, vb0, o[dt], 0, 0, 0);
      o[dt] = __builtin_amdgcn_mfma_f32_16x16x32_bf16(pa1, vb1, o[dt], 0, 0, 0);
    }
  }
  #pragma unroll
  for (int rg = 0; rg < 4; ++rg) {
    const float inv = 1.0f / l_i[rg];
    const int row = q0 + wave * 16 + quad * 4 + rg;
    float* op = Og + base + (size_t)row * DIM + ln;
    #pragma unroll
    for (int dt = 0; dt < 4; ++dt) op[dt * 16] = o[dt][rg] * inv;
  }
}

extern "C" void kernel_launch(void* const* d_in, const int* in_sizes, int n_in,
                              void* d_out, int out_size, void* d_ws, size_t ws_size,
                              hipStream_t stream) {
  (void)in_sizes; (void)n_in; (void)out_size;
  const float* Q = (const float*)d_in[0];
  const float* K = (const float*)d_in[1];
  const float* V = (const float*)d_in[2];
  float* O = (float*)d_out;
  const size_t need = (size_t)2 * BHN * SEQ * DIM * sizeof(__hip_bfloat16); // 16 MB
  if (ws_size >= need) {
    __hip_bfloat16* Kb = (__hip_bfloat16*)d_ws;
    __hip_bfloat16* Vt = Kb + (size_t)BHN * SEQ * DIM;
    prep_kernel<<<dim3(BHN, SEQ / 64), 256, 0, stream>>>(K, V, Kb, Vt);
    fattn7<<<dim3(BHN, SEQ / 64), 128, 0, stream>>>(Q, Kb, Vt, O);
  } else {
    fattn_ref<<<dim3(BHN, SEQ / 64), 256, 0, stream>>>(Q, K, V, O);
  }
}